// Round 18
// baseline (526.898 us; speedup 1.0000x reference)
//
#include <hip/hip_runtime.h>
#include <stdint.h>

#define M_NODES 100000
#define M_PAD   100096               // divisible by 128 (782 tiles of 128 rows)
#define NE      600000
#define DIM     128
#define NGRAPH  64
#define SCAN_B  512
#define SCAN_NB ((M_NODES + SCAN_B - 1) / SCAN_B)   // 196
#define WP      136   // sZ pitch in halves (row stride 272 B, 16B-aligned chunks)
#define FCHUNK  2048  // edges per fill-chunk; each chunk visited by 8 window-blocks
#define WINSZ   12500 // node-window per XCD slot

typedef __attribute__((ext_vector_type(8))) short short8;
typedef __attribute__((ext_vector_type(4))) float f32x4;

// ---- bf16 helpers (manual, RNE) ----
__device__ inline float bf2lo(uint32_t u) { return __uint_as_float(u << 16); }
__device__ inline float bf2hi(uint32_t u) { return __uint_as_float(u & 0xffff0000u); }
__device__ inline uint32_t packbf2(float a, float b) {
    uint32_t ua = __float_as_uint(a), ub = __float_as_uint(b);
    ua += 0x7fffu + ((ua >> 16) & 1u);
    ub += 0x7fffu + ((ub >> 16) & 1u);
    return (ua >> 16) | (ub & 0xffff0000u);
}
__device__ inline uint16_t ftobf16(float f) {
    uint32_t u = __float_as_uint(f);
    u += 0x7fffu + ((u >> 16) & 1u);
    return (uint16_t)(u >> 16);
}

// async 16B global->LDS copy (direct DMA, no VGPR round-trip); vmcnt-tracked,
// drained by the s_waitcnt before s_barrier. LDS dest = wave-uniform base +
// lane*16 (HW rule) -- caller must pass a lane-invariant lds pointer.
__device__ inline void async_copy16(const uint16_t* g, uint16_t* l) {
    __builtin_amdgcn_global_load_lds(
        (const __attribute__((address_space(1))) uint32_t*)g,
        (__attribute__((address_space(3))) uint32_t*)l, 16, 0, 0);
}

// ---- merged setup: embed + weight frag-order cvt + zero counters + graph bounds ----
// wfrag layout per layer L: [W1p, W1i, W2p, W2i], each 16384 halves in MFMA-fragment
// order: frag[((t*4+s)*64 + lane)*8 + j] = W[s*32+q*8+j][t*16+l16]  (lane = q*16+l16)
#define GB_EMBED 25000                 // M_NODES*64/256
#define GB_TRANS (GB_EMBED + 12)
#define GB_ZERO  (GB_TRANS + 391)
#define GB_BOUND (GB_ZERO + 391)
__global__ void k_setup(const int* __restrict__ x, const float2* __restrict__ te2,
                        const float2* __restrict__ oe2, uint32_t* __restrict__ h2,
                        const float* __restrict__ w1, const float* __restrict__ w2,
                        uint16_t* __restrict__ wfrag,
                        const int* __restrict__ batch, int* __restrict__ starts,
                        int* __restrict__ degp, int* __restrict__ degi,
                        int* __restrict__ curp, int* __restrict__ curi) {
    int b = blockIdx.x, t = threadIdx.x;
    if (b < GB_EMBED) {                       // node input embedding
        int id = b * 256 + t;
        int node = id >> 6, p = id & 63;
        int x0 = x[node * 2], x1 = x[node * 2 + 1];
        float2 a = te2[x0 * 64 + p], bb = oe2[x1 * 64 + p];
        h2[node * 64 + p] = packbf2(a.x + bb.x, a.y + bb.y);
    } else if (b < GB_TRANS) {                // frag-order cvt of 12 weight matrices
        int m = b - GB_EMBED;
        const float* src;
        uint16_t* dst;
        if (m < 6) {
            int L = m >> 1, rel = m & 1;
            src = w1 + m * 16384;
            dst = wfrag + (size_t)(L * 4 + rel) * 16384;
        } else {
            int mm = m - 6, L = mm >> 1, rel = mm & 1;
            src = w2 + mm * 16384;
            dst = wfrag + (size_t)(L * 4 + 2 + rel) * 16384;
        }
        for (int o = t; o < 16384; o += 256) {
            int f = o >> 3, j = o & 7;
            int fb = f >> 6, ln = f & 63;
            int t_ = fb >> 2, s_ = fb & 3, qq = ln >> 4, ll = ln & 15;
            dst[o] = ftobf16(src[(s_ * 32 + qq * 8 + j) * 128 + t_ * 16 + ll]);
        }
    } else if (b < GB_ZERO) {                 // zero scratch counters
        int i = (b - GB_TRANS) * 256 + t;
        if (i < M_NODES) { degp[i] = 0; degi[i] = 0; curp[i] = 0; curi[i] = 0; }
    } else {                                  // graph boundaries from sorted batch
        int i = (b - GB_ZERO) * 256 + t;
        if (i >= M_NODES) return;
        int bb = batch[i];
        int pb = (i == 0) ? -1 : batch[i - 1];
        for (int g = pb + 1; g <= bb; ++g) starts[g] = i;
        if (i == M_NODES - 1)
            for (int g = bb + 1; g <= NGRAPH; ++g) starts[g] = M_NODES;
    }
}

// ---- CSR build: histogram, 3-kernel scan, XCD-affine windowed fill ----
// edge-array reads are non-temporal: pure streams, keep them out of L2 so the
// scattered deg/cur/CSR lines stay resident and coalesce before writeback.
__global__ void k_hist(const int* __restrict__ ep, const int* __restrict__ ei,
                       int* __restrict__ degp, int* __restrict__ degi) {
    int e = blockIdx.x * blockDim.x + threadIdx.x;
    if (e >= NE) return;
    int dp = __builtin_nontemporal_load(ep + NE + e);
    int di = __builtin_nontemporal_load(ei + NE + e);
    atomicAdd(&degp[dp], 1);
    atomicAdd(&degi[di], 1);
}

__global__ void k_scan1(const int* __restrict__ degp, const int* __restrict__ degi,
                        int* __restrict__ rsp, int* __restrict__ rsi, int* __restrict__ bsum) {
    __shared__ int s[SCAN_B];
    int list = blockIdx.y;
    const int* deg = list ? degi : degp;
    int* rs = list ? rsi : rsp;
    int i = blockIdx.x * SCAN_B + threadIdx.x;
    int v = (i < M_NODES) ? deg[i] : 0;
    s[threadIdx.x] = v;
    __syncthreads();
    for (int off = 1; off < SCAN_B; off <<= 1) {
        int xv = (threadIdx.x >= off) ? s[threadIdx.x - off] : 0;
        __syncthreads();
        s[threadIdx.x] += xv;
        __syncthreads();
    }
    if (i < M_NODES) rs[i + 1] = s[threadIdx.x];
    if (threadIdx.x == SCAN_B - 1) bsum[list * SCAN_NB + blockIdx.x] = s[threadIdx.x];
}

__global__ void k_scan2(const int* __restrict__ bsum, int* __restrict__ boff) {
    __shared__ int s[256];
    int list = blockIdx.x, t = threadIdx.x;
    int v = (t < SCAN_NB) ? bsum[list * SCAN_NB + t] : 0;
    s[t] = v;
    __syncthreads();
    for (int off = 1; off < 256; off <<= 1) {
        int xv = (t >= off) ? s[t - off] : 0;
        __syncthreads();
        s[t] += xv;
        __syncthreads();
    }
    if (t < SCAN_NB) boff[list * SCAN_NB + t] = s[t] - v;  // exclusive
}

__global__ void k_scan3(int* __restrict__ rsp, int* __restrict__ rsi, const int* __restrict__ boff) {
    int list = blockIdx.y;
    int* rs = list ? rsi : rsp;
    int i = blockIdx.x * SCAN_B + threadIdx.x;
    if (i < M_NODES) rs[i + 1] += boff[list * SCAN_NB + blockIdx.x];
    if (i == 0 && list == 0) { rsp[0] = 0; rsi[0] = 0; }
}

// XCD-affine fill: block = (chunk, window); window = blockIdx&7 tracks the
// round-robin workgroup->XCD mapping, so each ~600KB CSR slice is dirtied by
// ONE XCD's L2. NT edge reads keep the stream from evicting those lines.
__global__ void k_fill(const int* __restrict__ ep, const int* __restrict__ ei,
                       const int* __restrict__ rsp, const int* __restrict__ rsi,
                       int* __restrict__ curp, int* __restrict__ curi,
                       int* __restrict__ csrp, int* __restrict__ csri) {
    int c = blockIdx.x >> 3;
    int w = blockIdx.x & 7;
    int lo = w * WINSZ;
    int hi = (w == 7) ? M_NODES : lo + WINSZ;
    int base = c * FCHUNK + threadIdx.x;
#pragma unroll
    for (int k = 0; k < FCHUNK / 256; ++k) {
        int e = base + k * 256;
        if (e < NE) {
            int dp = __builtin_nontemporal_load(ep + NE + e);
            if (dp >= lo && dp < hi) {
                int sp_ = __builtin_nontemporal_load(ep + e);
                int p = atomicAdd(&curp[dp], 1);
                csrp[rsp[dp] + p] = sp_;
            }
            int di = __builtin_nontemporal_load(ei + NE + e);
            if (di >= lo && di < hi) {
                int si_ = __builtin_nontemporal_load(ei + e);
                int p = atomicAdd(&curi[di], 1);
                csri[rsi[di] + p] = si_;
            }
        }
    }
}

// ---- fused dual-list aggregate: u = bf16(h + sum h[src]); 16 lanes x 8 dims per node ----
__device__ inline void add8(float* a, uint4 v) {
    a[0] += bf2lo(v.x); a[1] += bf2hi(v.x);
    a[2] += bf2lo(v.y); a[3] += bf2hi(v.y);
    a[4] += bf2lo(v.z); a[5] += bf2hi(v.z);
    a[6] += bf2lo(v.w); a[7] += bf2hi(v.w);
}

__device__ inline void gather_tail(const uint4* __restrict__ h4, const int* __restrict__ csr,
                                   int e, int e1, int p, float* a) {
    for (; e + 4 <= e1; e += 4) {
        int i0 = __builtin_nontemporal_load(csr + e);
        int i1 = __builtin_nontemporal_load(csr + e + 1);
        int i2 = __builtin_nontemporal_load(csr + e + 2);
        int i3 = __builtin_nontemporal_load(csr + e + 3);
        uint4 v0 = h4[(size_t)i0 * 16 + p];
        uint4 v1 = h4[(size_t)i1 * 16 + p];
        uint4 v2 = h4[(size_t)i2 * 16 + p];
        uint4 v3 = h4[(size_t)i3 * 16 + p];
        add8(a, v0); add8(a, v1); add8(a, v2); add8(a, v3);
    }
    for (; e < e1; ++e) add8(a, h4[(size_t)__builtin_nontemporal_load(csr + e) * 16 + p]);
}

__global__ void k_aggregate2(const uint4* __restrict__ h4,
                             const int* __restrict__ rsp, const int* __restrict__ csrp,
                             const int* __restrict__ rsi, const int* __restrict__ csri,
                             uint4* __restrict__ up, uint4* __restrict__ ui) {
    int id = blockIdx.x * blockDim.x + threadIdx.x;  // [0, M*16)
    int node = id >> 4, p = id & 15;
    if (node >= M_NODES) return;
    uint4 hv = h4[(size_t)node * 16 + p];
    float a[8] = {bf2lo(hv.x), bf2hi(hv.x), bf2lo(hv.y), bf2hi(hv.y),
                  bf2lo(hv.z), bf2hi(hv.z), bf2lo(hv.w), bf2hi(hv.w)};
    float b[8];
#pragma unroll
    for (int j = 0; j < 8; ++j) b[j] = a[j];
    int ea = rsp[node], e1a = rsp[node + 1];
    int eb = rsi[node], e1b = rsi[node + 1];
    // interleaved main loop: both relations in flight (4 row-gathers outstanding)
    while (ea + 2 <= e1a && eb + 2 <= e1b) {
        int ia0 = __builtin_nontemporal_load(csrp + ea);
        int ia1 = __builtin_nontemporal_load(csrp + ea + 1);
        int ib0 = __builtin_nontemporal_load(csri + eb);
        int ib1 = __builtin_nontemporal_load(csri + eb + 1);
        uint4 va0 = h4[(size_t)ia0 * 16 + p];
        uint4 va1 = h4[(size_t)ia1 * 16 + p];
        uint4 vb0 = h4[(size_t)ib0 * 16 + p];
        uint4 vb1 = h4[(size_t)ib1 * 16 + p];
        add8(a, va0); add8(a, va1); add8(b, vb0); add8(b, vb1);
        ea += 2; eb += 2;
    }
    gather_tail(h4, csrp, ea, e1a, p, a);
    gather_tail(h4, csri, eb, e1b, p, b);
    up[(size_t)node * 16 + p] = make_uint4(packbf2(a[0], a[1]), packbf2(a[2], a[3]),
                                           packbf2(a[4], a[5]), packbf2(a[6], a[7]));
    ui[(size_t)node * 16 + p] = make_uint4(packbf2(b[0], b[1]), packbf2(b[2], b[3]),
                                           packbf2(b[4], b[5]), packbf2(b[6], b[7]));
}

// ---- fused dual-relation MLP, 2 row-tiles (128 rows) per block ----
// r16 structure; weight staging via async global_load_lds (16B DMA).
__launch_bounds__(256, 2)
__global__ void k_gemm2(const uint16_t* __restrict__ Up, const uint16_t* __restrict__ Ui,
                        const uint16_t* __restrict__ WF1p, const float* __restrict__ B1p,
                        const uint16_t* __restrict__ WF2p, const float* __restrict__ B2p,
                        const uint16_t* __restrict__ WF1i, const float* __restrict__ B1i,
                        const uint16_t* __restrict__ WF2i, const float* __restrict__ B2i,
                        float* __restrict__ HN, uint16_t* __restrict__ HOUT, int last) {
    __shared__ __align__(16) uint16_t wbuf[16384];        // 32768 B, fragment-order
    __shared__ __align__(16) uint16_t sZ[2][64 * WP];     // 2 x 17408 B, wave-private
    int tid = threadIdx.x;
    int wave = tid >> 6, lane = tid & 63;
    int q = lane >> 4, l16 = lane & 15;
    int rb0 = blockIdx.x * 128 + wave * 16;   // tile 0 rows (this wave's 16)
    int rb1 = rb0 + 64;                       // tile 1 rows

    auto loadA = [&](const uint16_t* U, int rowbase, short8* v) {
        const uint16_t* P = U + (size_t)(rowbase + l16) * DIM + q * 8;
#pragma unroll
        for (int s = 0; s < 4; ++s) v[s] = *(const short8*)(P + s * 32);
    };
    // async weight staging: 8 x 16B per thread, direct global->LDS DMA.
    auto loadw = [&](const uint16_t* WF) {
#pragma unroll
        for (int k = 0; k < 8; ++k)
            async_copy16(WF + (size_t)(tid + k * 256) * 8,
                         &wbuf[(size_t)wave * 512 + (size_t)k * 2048]);
    };
    auto stage1 = [&](const short8* af, const float* B1, int zslot) {
        f32x4 acc1[8];
#pragma unroll
        for (int t = 0; t < 8; ++t) acc1[t] = (f32x4){0.f, 0.f, 0.f, 0.f};
#pragma unroll
        for (int t = 0; t < 8; ++t)
#pragma unroll
            for (int s = 0; s < 4; ++s) {
                short8 bb = *(const short8*)&wbuf[((t * 4 + s) * 64 + lane) * 8];
                acc1[t] = __builtin_amdgcn_mfma_f32_16x16x32_bf16(af[s], bb, acc1[t], 0, 0, 0);
            }
#pragma unroll
        for (int t = 0; t < 8; ++t) {
            float b1v = B1[t * 16 + l16];
#pragma unroll
            for (int r = 0; r < 4; ++r)
                sZ[zslot][(wave * 16 + q * 4 + r) * WP + t * 16 + l16] =
                    ftobf16(fmaxf(acc1[t][r] + b1v, 0.f));
        }
    };
    auto stage2 = [&](int zslot, f32x4* acc2) {
        short8 zf[4];
#pragma unroll
        for (int s = 0; s < 4; ++s)
            zf[s] = *(const short8*)&sZ[zslot][(wave * 16 + l16) * WP + s * 32 + q * 8];
#pragma unroll
        for (int t = 0; t < 8; ++t)
#pragma unroll
            for (int s = 0; s < 4; ++s) {
                short8 bb = *(const short8*)&wbuf[((t * 4 + s) * 64 + lane) * 8];
                acc2[t] = __builtin_amdgcn_mfma_f32_16x16x32_bf16(zf[s], bb, acc2[t], 0, 0, 0);
            }
    };

    f32x4 acc2a[8], acc2b[8];
#pragma unroll
    for (int t = 0; t < 8; ++t) { acc2a[t] = (f32x4){0.f,0.f,0.f,0.f}; acc2b[t] = (f32x4){0.f,0.f,0.f,0.f}; }

    short8 af0[4], af1[4];
    loadw(WF1p);                                       // async, in flight
    loadA(Up, rb0, af0); loadA(Up, rb1, af1);          // relation-p A frags in flight
    __syncthreads();                                   // drains vmcnt: wbuf = W1p
    stage1(af0, B1p, 0); stage1(af1, B1p, 1);
    __syncthreads();                                   // W1p reads done
    loadw(WF2p); __syncthreads();                      // wbuf = W2p
    stage2(0, acc2a); stage2(1, acc2b);
    __syncthreads();                                   // W2p reads done
    loadw(WF1i);                                       // async
    loadA(Ui, rb0, af0); loadA(Ui, rb1, af1);          // relation-i A frags
    __syncthreads();                                   // wbuf = W1i
    stage1(af0, B1i, 0); stage1(af1, B1i, 1);
    __syncthreads();
    loadw(WF2i); __syncthreads();                      // wbuf = W2i
    stage2(0, acc2a); stage2(1, acc2b);

    // epilogue, both tiles
#pragma unroll
    for (int t = 0; t < 8; ++t) {
        int col = t * 16 + l16;
        float b2v = B2p[col] + B2i[col];
#pragma unroll
        for (int r = 0; r < 4; ++r) {
            int row0 = rb0 + q * 4 + r, row1 = rb1 + q * 4 + r;
            float y0 = acc2a[t][r] + b2v, y1 = acc2b[t][r] + b2v;
            if (last) {
                HN[(size_t)row0 * DIM + col] = y0;
                HN[(size_t)row1 * DIM + col] = y1;
            } else {
                HOUT[(size_t)row0 * DIM + col] = ftobf16(fmaxf(y0, 0.f));
                HOUT[(size_t)row1 * DIM + col] = ftobf16(fmaxf(y1, 0.f));
            }
        }
    }
}

// ---- pooling, two-stage, high-parallelism (1024 + 64 blocks) ----
__global__ void k_pool1(const float* __restrict__ HN, const int* __restrict__ starts,
                        float* __restrict__ psum, float* __restrict__ pmax, float* __restrict__ pmin) {
    int g = blockIdx.x, sp = blockIdx.y, t = threadIdx.x;  // 256 threads = 2 row-slots x 128 dims
    int d = t & 127, rh = t >> 7;
    int slot = sp * 2 + rh;                                 // 0..31
    int s0 = starts[g], s1 = starts[g + 1];
    float s = 0.f, mx = -INFINITY, mn = INFINITY;
    for (int i = s0 + slot; i < s1; i += 32) {
        float v = HN[(size_t)i * DIM + d];
        s += v; mx = fmaxf(mx, v); mn = fminf(mn, v);
    }
    int o = (g * 32 + slot) * DIM + d;
    psum[o] = s; pmax[o] = mx; pmin[o] = mn;
}

__global__ void k_pool2(const float* __restrict__ psum, const float* __restrict__ pmax,
                        const float* __restrict__ pmin, const int* __restrict__ starts,
                        float* __restrict__ out) {
    __shared__ float S[4][128];
    int g = blockIdx.x, t = threadIdx.x;  // 128 threads
    float s = 0.f, mx = -INFINITY, mn = INFINITY;
    for (int p = 0; p < 32; ++p) {
        int o = (g * 32 + p) * DIM + t;
        s += psum[o]; mx = fmaxf(mx, pmax[o]); mn = fminf(mn, pmin[o]);
    }
    float cnt = (float)(starts[g + 1] - starts[g]);
    float mean = s / fmaxf(cnt, 1.f);
    S[0][t] = s; S[1][t] = mean; S[2][t] = mx; S[3][t] = mn;
    __syncthreads();
    // out[g,k,d] = concat[g, 4d+k]; concat = [sum|mean|max|min]
#pragma unroll
    for (int k = 0; k < 4; ++k) {
        int j = 4 * t + k;
        out[g * 512 + k * 128 + t] = S[j >> 7][j & 127];
    }
    if (t < 4) out[NGRAPH * 512 + g * 4 + t] = 1.0f;  // batch_mask = True -> 1.0f
}

extern "C" void kernel_launch(void* const* d_in, const int* in_sizes, int n_in,
                              void* d_out, int out_size, void* d_ws, size_t ws_size,
                              hipStream_t stream) {
    const int* x     = (const int*)d_in[0];
    const int* ep    = (const int*)d_in[1];
    const int* ei    = (const int*)d_in[2];
    const int* batch = (const int*)d_in[3];
    const float* te  = (const float*)d_in[4];
    const float* oe  = (const float*)d_in[5];
    const float* w1  = (const float*)d_in[6];
    const float* b1  = (const float*)d_in[7];
    const float* w2  = (const float*)d_in[8];
    const float* b2  = (const float*)d_in[9];
    float* out = (float*)d_out;

    char* w = (char*)d_ws;
    auto alloc = [&](size_t n) { char* p = w; w += (n + 255) & ~(size_t)255; return p; };
    uint16_t* h_bf  = (uint16_t*)alloc((size_t)M_PAD * DIM * 2);
    uint16_t* u_pos = (uint16_t*)alloc((size_t)M_PAD * DIM * 2);
    uint16_t* u_inv = (uint16_t*)alloc((size_t)M_PAD * DIM * 2);
    float*    hn    = (float*)alloc((size_t)M_PAD * DIM * 4);
    uint16_t* wfrag = (uint16_t*)alloc((size_t)12 * 16384 * 2);
    int* rsp  = (int*)alloc((M_NODES + 2) * 4);
    int* rsi  = (int*)alloc((M_NODES + 2) * 4);
    int* degp = (int*)alloc(M_NODES * 4);
    int* degi = (int*)alloc(M_NODES * 4);
    int* curp = (int*)alloc(M_NODES * 4);
    int* curi = (int*)alloc(M_NODES * 4);
    int* csrp = (int*)alloc((size_t)NE * 4);
    int* csri = (int*)alloc((size_t)NE * 4);
    int* bsum = (int*)alloc(2 * SCAN_NB * 4);
    int* boff = (int*)alloc(2 * SCAN_NB * 4);
    int* starts = (int*)alloc((NGRAPH + 1) * 4);
    float* psum = (float*)alloc(NGRAPH * 32 * DIM * 4);
    float* pmax = (float*)alloc(NGRAPH * 32 * DIM * 4);
    float* pmin = (float*)alloc(NGRAPH * 32 * DIM * 4);
    if ((size_t)(w - (char*)d_ws) > ws_size) return;  // fail loudly rather than corrupt

    k_setup<<<GB_BOUND, 256, 0, stream>>>(x, (const float2*)te, (const float2*)oe,
                                          (uint32_t*)h_bf, w1, w2, wfrag,
                                          batch, starts, degp, degi, curp, curi);
    k_hist<<<(NE + 255) / 256, 256, 0, stream>>>(ep, ei, degp, degi);
    dim3 gs(SCAN_NB, 2);
    k_scan1<<<gs, SCAN_B, 0, stream>>>(degp, degi, rsp, rsi, bsum);
    k_scan2<<<2, 256, 0, stream>>>(bsum, boff);
    k_scan3<<<gs, SCAN_B, 0, stream>>>(rsp, rsi, boff);
    k_fill<<<((NE + FCHUNK - 1) / FCHUNK) * 8, 256, 0, stream>>>(
        ep, ei, rsp, rsi, curp, curi, csrp, csri);

    for (int l = 0; l < 3; ++l) {
        k_aggregate2<<<(M_NODES * 16 + 255) / 256, 256, 0, stream>>>(
            (const uint4*)h_bf, rsp, csrp, rsi, csri, (uint4*)u_pos, (uint4*)u_inv);
        const uint16_t* wfL = wfrag + (size_t)l * 4 * 16384;
        // wfrag per layer: [W1p, W1i, W2p, W2i]
        k_gemm2<<<M_PAD / 128, 256, 0, stream>>>(
            u_pos, u_inv,
            wfL,              b1 + (2 * l) * 128,
            wfL + 2 * 16384,  b2 + (2 * l) * 128,
            wfL + 16384,      b1 + (2 * l + 1) * 128,
            wfL + 3 * 16384,  b2 + (2 * l + 1) * 128,
            hn, h_bf, (l == 2) ? 1 : 0);
    }
    dim3 gp(NGRAPH, 16);
    k_pool1<<<gp, 256, 0, stream>>>(hn, starts, psum, pmax, pmin);
    k_pool2<<<NGRAPH, 128, 0, stream>>>(psum, pmax, pmin, starts, out);
}

// Round 19
// 493.709 us; speedup vs baseline: 1.0672x; 1.0672x over previous
//
#include <hip/hip_runtime.h>
#include <stdint.h>

#define M_NODES 100000
#define M_PAD   100096               // divisible by 128 (782 tiles of 128 rows)
#define NE      600000
#define DIM     128
#define NGRAPH  64
#define SCAN_B  512
#define SCAN_NB ((M_NODES + SCAN_B - 1) / SCAN_B)   // 196
#define WP      136   // sZ pitch in halves (row stride 272 B, 16B-aligned chunks)
#define FCHUNK  2048  // edges per fill-chunk; each chunk visited by 8 window-blocks
#define WINSZ   12500 // node-window per XCD slot

typedef __attribute__((ext_vector_type(8))) short short8;
typedef __attribute__((ext_vector_type(4))) float f32x4;

// ---- bf16 helpers (manual, RNE) ----
__device__ inline float bf2lo(uint32_t u) { return __uint_as_float(u << 16); }
__device__ inline float bf2hi(uint32_t u) { return __uint_as_float(u & 0xffff0000u); }
__device__ inline uint32_t packbf2(float a, float b) {
    uint32_t ua = __float_as_uint(a), ub = __float_as_uint(b);
    ua += 0x7fffu + ((ua >> 16) & 1u);
    ub += 0x7fffu + ((ub >> 16) & 1u);
    return (ua >> 16) | (ub & 0xffff0000u);
}
__device__ inline uint16_t ftobf16(float f) {
    uint32_t u = __float_as_uint(f);
    u += 0x7fffu + ((u >> 16) & 1u);
    return (uint16_t)(u >> 16);
}

// async 16B global->LDS copy (direct DMA, no VGPR round-trip); vmcnt-tracked,
// drained by the s_waitcnt before s_barrier. LDS dest = wave-uniform base +
// lane*16 (HW rule) -- caller must pass a lane-invariant lds pointer.
__device__ inline void async_copy16(const uint16_t* g, uint16_t* l) {
    __builtin_amdgcn_global_load_lds(
        (const __attribute__((address_space(1))) uint32_t*)g,
        (__attribute__((address_space(3))) uint32_t*)l, 16, 0, 0);
}

// ---- merged setup: embed + weight frag-order cvt + zero counters + graph bounds ----
// wfrag layout per layer L: [W1p, W1i, W2p, W2i], each 16384 halves in MFMA-fragment
// order: frag[((t*4+s)*64 + lane)*8 + j] = W[s*32+q*8+j][t*16+l16]  (lane = q*16+l16)
#define GB_EMBED 25000                 // M_NODES*64/256
#define GB_TRANS (GB_EMBED + 12)
#define GB_ZERO  (GB_TRANS + 391)
#define GB_BOUND (GB_ZERO + 391)
__global__ void k_setup(const int* __restrict__ x, const float2* __restrict__ te2,
                        const float2* __restrict__ oe2, uint32_t* __restrict__ h2,
                        const float* __restrict__ w1, const float* __restrict__ w2,
                        uint16_t* __restrict__ wfrag,
                        const int* __restrict__ batch, int* __restrict__ starts,
                        int* __restrict__ degp, int* __restrict__ degi,
                        int* __restrict__ curp, int* __restrict__ curi) {
    int b = blockIdx.x, t = threadIdx.x;
    if (b < GB_EMBED) {                       // node input embedding
        int id = b * 256 + t;
        int node = id >> 6, p = id & 63;
        int x0 = x[node * 2], x1 = x[node * 2 + 1];
        float2 a = te2[x0 * 64 + p], bb = oe2[x1 * 64 + p];
        h2[node * 64 + p] = packbf2(a.x + bb.x, a.y + bb.y);
    } else if (b < GB_TRANS) {                // frag-order cvt of 12 weight matrices
        int m = b - GB_EMBED;
        const float* src;
        uint16_t* dst;
        if (m < 6) {
            int L = m >> 1, rel = m & 1;
            src = w1 + m * 16384;
            dst = wfrag + (size_t)(L * 4 + rel) * 16384;
        } else {
            int mm = m - 6, L = mm >> 1, rel = mm & 1;
            src = w2 + mm * 16384;
            dst = wfrag + (size_t)(L * 4 + 2 + rel) * 16384;
        }
        for (int o = t; o < 16384; o += 256) {
            int f = o >> 3, j = o & 7;
            int fb = f >> 6, ln = f & 63;
            int t_ = fb >> 2, s_ = fb & 3, qq = ln >> 4, ll = ln & 15;
            dst[o] = ftobf16(src[(s_ * 32 + qq * 8 + j) * 128 + t_ * 16 + ll]);
        }
    } else if (b < GB_ZERO) {                 // zero scratch counters
        int i = (b - GB_TRANS) * 256 + t;
        if (i < M_NODES) { degp[i] = 0; degi[i] = 0; curp[i] = 0; curi[i] = 0; }
    } else {                                  // graph boundaries from sorted batch
        int i = (b - GB_ZERO) * 256 + t;
        if (i >= M_NODES) return;
        int bb = batch[i];
        int pb = (i == 0) ? -1 : batch[i - 1];
        for (int g = pb + 1; g <= bb; ++g) starts[g] = i;
        if (i == M_NODES - 1)
            for (int g = bb + 1; g <= NGRAPH; ++g) starts[g] = M_NODES;
    }
}

// ---- CSR build: histogram, 3-kernel scan, XCD-affine windowed fill ----
__global__ void k_hist(const int* __restrict__ ep, const int* __restrict__ ei,
                       int* __restrict__ degp, int* __restrict__ degi) {
    int e = blockIdx.x * blockDim.x + threadIdx.x;
    if (e >= NE) return;
    atomicAdd(&degp[ep[NE + e]], 1);
    atomicAdd(&degi[ei[NE + e]], 1);
}

__global__ void k_scan1(const int* __restrict__ degp, const int* __restrict__ degi,
                        int* __restrict__ rsp, int* __restrict__ rsi, int* __restrict__ bsum) {
    __shared__ int s[SCAN_B];
    int list = blockIdx.y;
    const int* deg = list ? degi : degp;
    int* rs = list ? rsi : rsp;
    int i = blockIdx.x * SCAN_B + threadIdx.x;
    int v = (i < M_NODES) ? deg[i] : 0;
    s[threadIdx.x] = v;
    __syncthreads();
    for (int off = 1; off < SCAN_B; off <<= 1) {
        int xv = (threadIdx.x >= off) ? s[threadIdx.x - off] : 0;
        __syncthreads();
        s[threadIdx.x] += xv;
        __syncthreads();
    }
    if (i < M_NODES) rs[i + 1] = s[threadIdx.x];
    if (threadIdx.x == SCAN_B - 1) bsum[list * SCAN_NB + blockIdx.x] = s[threadIdx.x];
}

__global__ void k_scan2(const int* __restrict__ bsum, int* __restrict__ boff) {
    __shared__ int s[256];
    int list = blockIdx.x, t = threadIdx.x;
    int v = (t < SCAN_NB) ? bsum[list * SCAN_NB + t] : 0;
    s[t] = v;
    __syncthreads();
    for (int off = 1; off < 256; off <<= 1) {
        int xv = (t >= off) ? s[t - off] : 0;
        __syncthreads();
        s[t] += xv;
        __syncthreads();
    }
    if (t < SCAN_NB) boff[list * SCAN_NB + t] = s[t] - v;  // exclusive
}

__global__ void k_scan3(int* __restrict__ rsp, int* __restrict__ rsi, const int* __restrict__ boff) {
    int list = blockIdx.y;
    int* rs = list ? rsi : rsp;
    int i = blockIdx.x * SCAN_B + threadIdx.x;
    if (i < M_NODES) rs[i + 1] += boff[list * SCAN_NB + blockIdx.x];
    if (i == 0 && list == 0) { rsp[0] = 0; rsi[0] = 0; }
}

// XCD-affine fill: block = (chunk, window); window = blockIdx&7 tracks the
// round-robin workgroup->XCD mapping, so each ~600KB CSR slice is dirtied by
// ONE XCD's L2 (kills cross-XCD false sharing on CSR lines).
__global__ void k_fill(const int* __restrict__ ep, const int* __restrict__ ei,
                       const int* __restrict__ rsp, const int* __restrict__ rsi,
                       int* __restrict__ curp, int* __restrict__ curi,
                       int* __restrict__ csrp, int* __restrict__ csri) {
    int c = blockIdx.x >> 3;
    int w = blockIdx.x & 7;
    int lo = w * WINSZ;
    int hi = (w == 7) ? M_NODES : lo + WINSZ;
    int base = c * FCHUNK + threadIdx.x;
#pragma unroll
    for (int k = 0; k < FCHUNK / 256; ++k) {
        int e = base + k * 256;
        if (e < NE) {
            int dp = ep[NE + e], sp_ = ep[e];
            if (dp >= lo && dp < hi) { int p = atomicAdd(&curp[dp], 1); csrp[rsp[dp] + p] = sp_; }
            int di = ei[NE + e], si_ = ei[e];
            if (di >= lo && di < hi) { int p = atomicAdd(&curi[di], 1); csri[rsi[di] + p] = si_; }
        }
    }
}

// ---- fused dual-list aggregate: u = bf16(h + sum h[src]); 16 lanes x 8 dims per node ----
__device__ inline void add8(float* a, uint4 v) {
    a[0] += bf2lo(v.x); a[1] += bf2hi(v.x);
    a[2] += bf2lo(v.y); a[3] += bf2hi(v.y);
    a[4] += bf2lo(v.z); a[5] += bf2hi(v.z);
    a[6] += bf2lo(v.w); a[7] += bf2hi(v.w);
}

__device__ inline void gather_tail(const uint4* __restrict__ h4, const int* __restrict__ csr,
                                   int e, int e1, int p, float* a) {
    for (; e + 4 <= e1; e += 4) {
        int i0 = csr[e], i1 = csr[e + 1], i2 = csr[e + 2], i3 = csr[e + 3];
        uint4 v0 = h4[(size_t)i0 * 16 + p];
        uint4 v1 = h4[(size_t)i1 * 16 + p];
        uint4 v2 = h4[(size_t)i2 * 16 + p];
        uint4 v3 = h4[(size_t)i3 * 16 + p];
        add8(a, v0); add8(a, v1); add8(a, v2); add8(a, v3);
    }
    for (; e < e1; ++e) add8(a, h4[(size_t)csr[e] * 16 + p]);
}

__global__ void k_aggregate2(const uint4* __restrict__ h4,
                             const int* __restrict__ rsp, const int* __restrict__ csrp,
                             const int* __restrict__ rsi, const int* __restrict__ csri,
                             uint4* __restrict__ up, uint4* __restrict__ ui) {
    int id = blockIdx.x * blockDim.x + threadIdx.x;  // [0, M*16)
    int node = id >> 4, p = id & 15;
    if (node >= M_NODES) return;
    uint4 hv = h4[(size_t)node * 16 + p];
    float a[8] = {bf2lo(hv.x), bf2hi(hv.x), bf2lo(hv.y), bf2hi(hv.y),
                  bf2lo(hv.z), bf2hi(hv.z), bf2lo(hv.w), bf2hi(hv.w)};
    float b[8];
#pragma unroll
    for (int j = 0; j < 8; ++j) b[j] = a[j];
    int ea = rsp[node], e1a = rsp[node + 1];
    int eb = rsi[node], e1b = rsi[node + 1];
    // interleaved main loop: both relations in flight (4 row-gathers outstanding)
    while (ea + 2 <= e1a && eb + 2 <= e1b) {
        int ia0 = csrp[ea], ia1 = csrp[ea + 1];
        int ib0 = csri[eb], ib1 = csri[eb + 1];
        uint4 va0 = h4[(size_t)ia0 * 16 + p];
        uint4 va1 = h4[(size_t)ia1 * 16 + p];
        uint4 vb0 = h4[(size_t)ib0 * 16 + p];
        uint4 vb1 = h4[(size_t)ib1 * 16 + p];
        add8(a, va0); add8(a, va1); add8(b, vb0); add8(b, vb1);
        ea += 2; eb += 2;
    }
    gather_tail(h4, csrp, ea, e1a, p, a);
    gather_tail(h4, csri, eb, e1b, p, b);
    up[(size_t)node * 16 + p] = make_uint4(packbf2(a[0], a[1]), packbf2(a[2], a[3]),
                                           packbf2(a[4], a[5]), packbf2(a[6], a[7]));
    ui[(size_t)node * 16 + p] = make_uint4(packbf2(b[0], b[1]), packbf2(b[2], b[3]),
                                           packbf2(b[4], b[5]), packbf2(b[6], b[7]));
}

// ---- fused dual-relation MLP, 2 row-tiles (128 rows) per block ----
// r16 structure; weight staging via async global_load_lds (16B DMA).
__launch_bounds__(256, 2)
__global__ void k_gemm2(const uint16_t* __restrict__ Up, const uint16_t* __restrict__ Ui,
                        const uint16_t* __restrict__ WF1p, const float* __restrict__ B1p,
                        const uint16_t* __restrict__ WF2p, const float* __restrict__ B2p,
                        const uint16_t* __restrict__ WF1i, const float* __restrict__ B1i,
                        const uint16_t* __restrict__ WF2i, const float* __restrict__ B2i,
                        float* __restrict__ HN, uint16_t* __restrict__ HOUT, int last) {
    __shared__ __align__(16) uint16_t wbuf[16384];        // 32768 B, fragment-order
    __shared__ __align__(16) uint16_t sZ[2][64 * WP];     // 2 x 17408 B, wave-private
    int tid = threadIdx.x;
    int wave = tid >> 6, lane = tid & 63;
    int q = lane >> 4, l16 = lane & 15;
    int rb0 = blockIdx.x * 128 + wave * 16;   // tile 0 rows (this wave's 16)
    int rb1 = rb0 + 64;                       // tile 1 rows

    auto loadA = [&](const uint16_t* U, int rowbase, short8* v) {
        const uint16_t* P = U + (size_t)(rowbase + l16) * DIM + q * 8;
#pragma unroll
        for (int s = 0; s < 4; ++s) v[s] = *(const short8*)(P + s * 32);
    };
    // async weight staging: 8 x 16B per thread, direct global->LDS DMA.
    auto loadw = [&](const uint16_t* WF) {
#pragma unroll
        for (int k = 0; k < 8; ++k)
            async_copy16(WF + (size_t)(tid + k * 256) * 8,
                         &wbuf[(size_t)wave * 512 + (size_t)k * 2048]);
    };
    auto stage1 = [&](const short8* af, const float* B1, int zslot) {
        f32x4 acc1[8];
#pragma unroll
        for (int t = 0; t < 8; ++t) acc1[t] = (f32x4){0.f, 0.f, 0.f, 0.f};
#pragma unroll
        for (int t = 0; t < 8; ++t)
#pragma unroll
            for (int s = 0; s < 4; ++s) {
                short8 bb = *(const short8*)&wbuf[((t * 4 + s) * 64 + lane) * 8];
                acc1[t] = __builtin_amdgcn_mfma_f32_16x16x32_bf16(af[s], bb, acc1[t], 0, 0, 0);
            }
#pragma unroll
        for (int t = 0; t < 8; ++t) {
            float b1v = B1[t * 16 + l16];
#pragma unroll
            for (int r = 0; r < 4; ++r)
                sZ[zslot][(wave * 16 + q * 4 + r) * WP + t * 16 + l16] =
                    ftobf16(fmaxf(acc1[t][r] + b1v, 0.f));
        }
    };
    auto stage2 = [&](int zslot, f32x4* acc2) {
        short8 zf[4];
#pragma unroll
        for (int s = 0; s < 4; ++s)
            zf[s] = *(const short8*)&sZ[zslot][(wave * 16 + l16) * WP + s * 32 + q * 8];
#pragma unroll
        for (int t = 0; t < 8; ++t)
#pragma unroll
            for (int s = 0; s < 4; ++s) {
                short8 bb = *(const short8*)&wbuf[((t * 4 + s) * 64 + lane) * 8];
                acc2[t] = __builtin_amdgcn_mfma_f32_16x16x32_bf16(zf[s], bb, acc2[t], 0, 0, 0);
            }
    };

    f32x4 acc2a[8], acc2b[8];
#pragma unroll
    for (int t = 0; t < 8; ++t) { acc2a[t] = (f32x4){0.f,0.f,0.f,0.f}; acc2b[t] = (f32x4){0.f,0.f,0.f,0.f}; }

    short8 af0[4], af1[4];
    loadw(WF1p);                                       // async, in flight
    loadA(Up, rb0, af0); loadA(Up, rb1, af1);          // relation-p A frags in flight
    __syncthreads();                                   // drains vmcnt: wbuf = W1p
    stage1(af0, B1p, 0); stage1(af1, B1p, 1);
    __syncthreads();                                   // W1p reads done
    loadw(WF2p); __syncthreads();                      // wbuf = W2p
    stage2(0, acc2a); stage2(1, acc2b);
    __syncthreads();                                   // W2p reads done
    loadw(WF1i);                                       // async
    loadA(Ui, rb0, af0); loadA(Ui, rb1, af1);          // relation-i A frags
    __syncthreads();                                   // wbuf = W1i
    stage1(af0, B1i, 0); stage1(af1, B1i, 1);
    __syncthreads();
    loadw(WF2i); __syncthreads();                      // wbuf = W2i
    stage2(0, acc2a); stage2(1, acc2b);

    // epilogue, both tiles
#pragma unroll
    for (int t = 0; t < 8; ++t) {
        int col = t * 16 + l16;
        float b2v = B2p[col] + B2i[col];
#pragma unroll
        for (int r = 0; r < 4; ++r) {
            int row0 = rb0 + q * 4 + r, row1 = rb1 + q * 4 + r;
            float y0 = acc2a[t][r] + b2v, y1 = acc2b[t][r] + b2v;
            if (last) {
                HN[(size_t)row0 * DIM + col] = y0;
                HN[(size_t)row1 * DIM + col] = y1;
            } else {
                HOUT[(size_t)row0 * DIM + col] = ftobf16(fmaxf(y0, 0.f));
                HOUT[(size_t)row1 * DIM + col] = ftobf16(fmaxf(y1, 0.f));
            }
        }
    }
}

// ---- pooling, two-stage, high-parallelism (1024 + 64 blocks) ----
__global__ void k_pool1(const float* __restrict__ HN, const int* __restrict__ starts,
                        float* __restrict__ psum, float* __restrict__ pmax, float* __restrict__ pmin) {
    int g = blockIdx.x, sp = blockIdx.y, t = threadIdx.x;  // 256 threads = 2 row-slots x 128 dims
    int d = t & 127, rh = t >> 7;
    int slot = sp * 2 + rh;                                 // 0..31
    int s0 = starts[g], s1 = starts[g + 1];
    float s = 0.f, mx = -INFINITY, mn = INFINITY;
    for (int i = s0 + slot; i < s1; i += 32) {
        float v = HN[(size_t)i * DIM + d];
        s += v; mx = fmaxf(mx, v); mn = fminf(mn, v);
    }
    int o = (g * 32 + slot) * DIM + d;
    psum[o] = s; pmax[o] = mx; pmin[o] = mn;
}

__global__ void k_pool2(const float* __restrict__ psum, const float* __restrict__ pmax,
                        const float* __restrict__ pmin, const int* __restrict__ starts,
                        float* __restrict__ out) {
    __shared__ float S[4][128];
    int g = blockIdx.x, t = threadIdx.x;  // 128 threads
    float s = 0.f, mx = -INFINITY, mn = INFINITY;
    for (int p = 0; p < 32; ++p) {
        int o = (g * 32 + p) * DIM + t;
        s += psum[o]; mx = fmaxf(mx, pmax[o]); mn = fminf(mn, pmin[o]);
    }
    float cnt = (float)(starts[g + 1] - starts[g]);
    float mean = s / fmaxf(cnt, 1.f);
    S[0][t] = s; S[1][t] = mean; S[2][t] = mx; S[3][t] = mn;
    __syncthreads();
    // out[g,k,d] = concat[g, 4d+k]; concat = [sum|mean|max|min]
#pragma unroll
    for (int k = 0; k < 4; ++k) {
        int j = 4 * t + k;
        out[g * 512 + k * 128 + t] = S[j >> 7][j & 127];
    }
    if (t < 4) out[NGRAPH * 512 + g * 4 + t] = 1.0f;  // batch_mask = True -> 1.0f
}

extern "C" void kernel_launch(void* const* d_in, const int* in_sizes, int n_in,
                              void* d_out, int out_size, void* d_ws, size_t ws_size,
                              hipStream_t stream) {
    const int* x     = (const int*)d_in[0];
    const int* ep    = (const int*)d_in[1];
    const int* ei    = (const int*)d_in[2];
    const int* batch = (const int*)d_in[3];
    const float* te  = (const float*)d_in[4];
    const float* oe  = (const float*)d_in[5];
    const float* w1  = (const float*)d_in[6];
    const float* b1  = (const float*)d_in[7];
    const float* w2  = (const float*)d_in[8];
    const float* b2  = (const float*)d_in[9];
    float* out = (float*)d_out;

    char* w = (char*)d_ws;
    auto alloc = [&](size_t n) { char* p = w; w += (n + 255) & ~(size_t)255; return p; };
    uint16_t* h_bf  = (uint16_t*)alloc((size_t)M_PAD * DIM * 2);
    uint16_t* u_pos = (uint16_t*)alloc((size_t)M_PAD * DIM * 2);
    uint16_t* u_inv = (uint16_t*)alloc((size_t)M_PAD * DIM * 2);
    float*    hn    = (float*)alloc((size_t)M_PAD * DIM * 4);
    uint16_t* wfrag = (uint16_t*)alloc((size_t)12 * 16384 * 2);
    int* rsp  = (int*)alloc((M_NODES + 2) * 4);
    int* rsi  = (int*)alloc((M_NODES + 2) * 4);
    int* degp = (int*)alloc(M_NODES * 4);
    int* degi = (int*)alloc(M_NODES * 4);
    int* curp = (int*)alloc(M_NODES * 4);
    int* curi = (int*)alloc(M_NODES * 4);
    int* csrp = (int*)alloc((size_t)NE * 4);
    int* csri = (int*)alloc((size_t)NE * 4);
    int* bsum = (int*)alloc(2 * SCAN_NB * 4);
    int* boff = (int*)alloc(2 * SCAN_NB * 4);
    int* starts = (int*)alloc((NGRAPH + 1) * 4);
    float* psum = (float*)alloc(NGRAPH * 32 * DIM * 4);
    float* pmax = (float*)alloc(NGRAPH * 32 * DIM * 4);
    float* pmin = (float*)alloc(NGRAPH * 32 * DIM * 4);
    if ((size_t)(w - (char*)d_ws) > ws_size) return;  // fail loudly rather than corrupt

    k_setup<<<GB_BOUND, 256, 0, stream>>>(x, (const float2*)te, (const float2*)oe,
                                          (uint32_t*)h_bf, w1, w2, wfrag,
                                          batch, starts, degp, degi, curp, curi);
    k_hist<<<(NE + 255) / 256, 256, 0, stream>>>(ep, ei, degp, degi);
    dim3 gs(SCAN_NB, 2);
    k_scan1<<<gs, SCAN_B, 0, stream>>>(degp, degi, rsp, rsi, bsum);
    k_scan2<<<2, 256, 0, stream>>>(bsum, boff);
    k_scan3<<<gs, SCAN_B, 0, stream>>>(rsp, rsi, boff);
    k_fill<<<((NE + FCHUNK - 1) / FCHUNK) * 8, 256, 0, stream>>>(
        ep, ei, rsp, rsi, curp, curi, csrp, csri);

    for (int l = 0; l < 3; ++l) {
        k_aggregate2<<<(M_NODES * 16 + 255) / 256, 256, 0, stream>>>(
            (const uint4*)h_bf, rsp, csrp, rsi, csri, (uint4*)u_pos, (uint4*)u_inv);
        const uint16_t* wfL = wfrag + (size_t)l * 4 * 16384;
        // wfrag per layer: [W1p, W1i, W2p, W2i]
        k_gemm2<<<M_PAD / 128, 256, 0, stream>>>(
            u_pos, u_inv,
            wfL,              b1 + (2 * l) * 128,
            wfL + 2 * 16384,  b2 + (2 * l) * 128,
            wfL + 16384,      b1 + (2 * l + 1) * 128,
            wfL + 3 * 16384,  b2 + (2 * l + 1) * 128,
            hn, h_bf, (l == 2) ? 1 : 0);
    }
    dim3 gp(NGRAPH, 16);
    k_pool1<<<gp, 256, 0, stream>>>(hn, starts, psum, pmax, pmin);
    k_pool2<<<NGRAPH, 128, 0, stream>>>(psum, pmax, pmin, starts, out);
}